// Round 1
// baseline (342.957 us; speedup 1.0000x reference)
//
#include <hip/hip_runtime.h>
#include <cmath>

#define RAYS_PER_BLOCK 2

__device__ __forceinline__ float sigm(float x){ return 1.0f/(1.0f + expf(-x)); }
__device__ __forceinline__ float clampf(float x, float lo, float hi){ return fminf(fmaxf(x, lo), hi); }
__device__ __forceinline__ float f4get(const float4 v, int e){
  return e==0 ? v.x : (e==1 ? v.y : (e==2 ? v.z : v.w));
}

// One block = 2 rays x 128 threads. Fine sample s = thread lt (0..127).
// Weights staged once per block in LDS; all weight reads are wave-uniform (broadcast).
__global__ __launch_bounds__(256)
void neus_render(const float* __restrict__ rays_o, const float* __restrict__ rays_d,
                 const float* __restrict__ W1, const float* __restrict__ b1,
                 const float* __restrict__ W2, const float* __restrict__ b2,
                 const float* __restrict__ Wc1, const float* __restrict__ bc1,
                 const float* __restrict__ Wc2, const float* __restrict__ bc2,
                 const float* __restrict__ inv_s_p, float* __restrict__ out)
{
  __shared__ float4 sW1p[64];        // {W1[0][j], W1[1][j], W1[2][j], b1[j]}
  __shared__ float4 sW2v4[64*17];    // W2 row j, cols 4c..4c+3 (65 cols padded to 68)
  __shared__ float4 sb2p[17];        // b2 padded to 68
  __shared__ float  sw2c0[64];       // W2[:,0] (sdf column, used by gradient evals)
  __shared__ float4 sWc1T[64*19];    // per hidden j: cin-ordered [pt3,dir3,n3,feat64,pad3]
  __shared__ float4 sWc2p[64];       // {Wc2[j][0..2], 0}
  __shared__ float  sbc1[64];
  __shared__ float  s_z[RAYS_PER_BLOCK][64];     // coarse z (sorted)
  __shared__ float  s_cdf[RAYS_PER_BLOCK][64];   // sample_pdf cdf (K=64)
  __shared__ float  s_newz[RAYS_PER_BLOCK][64];  // importance samples (sorted)
  __shared__ float  s_zall[RAYS_PER_BLOCK][128]; // merged sorted z
  __shared__ float  s_red[RAYS_PER_BLOCK][2][4];
  __shared__ float  s_wtot[RAYS_PER_BLOCK][2];

  const int tid  = threadIdx.x;
  const int rs   = tid >> 7;          // ray slot in block
  const int lt   = tid & 127;         // thread within ray
  const int lane = tid & 63;
  const int wir  = (tid >> 6) & 1;    // wave within ray
  const int ray  = blockIdx.x * RAYS_PER_BLOCK + rs;

  // ---- stage weights into LDS ----
  for (int i = tid; i < 64; i += 256){
    sW1p[i]  = make_float4(W1[i], W1[64+i], W1[128+i], b1[i]);
    sw2c0[i] = W2[i*65];
    sbc1[i]  = bc1[i];
    sWc2p[i] = make_float4(Wc2[i*3], Wc2[i*3+1], Wc2[i*3+2], 0.f);
  }
  {
    float* p = (float*)sW2v4;
    for (int i = tid; i < 64*68; i += 256){
      int j = i/68, k = i - j*68;
      p[i] = (k < 65) ? W2[j*65+k] : 0.f;
    }
    float* q = (float*)sb2p;
    for (int i = tid; i < 68; i += 256) q[i] = (i < 65) ? b2[i] : 0.f;
    float* t = (float*)sWc1T;
    for (int i = tid; i < 64*76; i += 256){
      int j = i/76, c = i - j*76;
      t[i] = (c < 73) ? Wc1[c*64 + j] : 0.f;   // transpose: row j = column j of Wc1
    }
  }

  // ---- per-ray setup (every thread) ----
  float ox = rays_o[ray*3], oy = rays_o[ray*3+1], oz = rays_o[ray*3+2];
  float dx = rays_d[ray*3], dy = rays_d[ray*3+1], dz = rays_d[ray*3+2];
  float tnx = (-1.f-ox)/(dx+1e-15f), tfx = (1.f-ox)/(dx+1e-15f);
  float tny = (-1.f-oy)/(dy+1e-15f), tfy = (1.f-oy)/(dy+1e-15f);
  float tnz = (-1.f-oz)/(dz+1e-15f), tfz = (1.f-oz)/(dz+1e-15f);
  float nearv = fmaxf(fmaxf(fminf(tnx,tfx), fminf(tny,tfy)), fminf(tnz,tfz));
  float farv  = fminf(fminf(fmaxf(tnx,tfx), fmaxf(tny,tfy)), fmaxf(tnz,tfz));
  nearv = fmaxf(nearv, 0.05f);
  const float sd = (farv - nearv) * (1.f/64.f);

  __syncthreads();
  const float b20 = ((const float*)sb2p)[0];

  // ---- coarse pass: wave 0 of each ray, lane = coarse sample t ----
  if (wir == 0){
    float zt = nearv + (farv-nearv) * ((float)lane * (1.f/63.f));
    float px = clampf(ox + dx*zt, -1.f, 1.f);
    float py = clampf(oy + dy*zt, -1.f, 1.f);
    float pz = clampf(oz + dz*zt, -1.f, 1.f);
    float acc = b20;
    #pragma unroll 8
    for (int j = 0; j < 64; ++j){
      float4 w = sW1p[j];
      acc += fmaxf(px*w.x + py*w.y + pz*w.z + w.w, 0.f) * sw2c0[j];
    }
    s_z[rs][lane] = zt;
    float s1  = __shfl_down(acc, 1);
    float zt1 = nearv + (farv-nearv) * ((float)(lane+1) * (1.f/63.f));
    float a_c = 0.f, qv = 1.f;
    if (lane < 63){
      float dc   = zt1 - zt;
      float mid  = 0.5f*(acc + s1);
      float cosv = clampf((s1-acc)/(dc+1e-5f), -1000.f, 0.f);
      float est  = cosv*dc*0.5f;
      float pcv  = sigm((mid-est)*64.f);
      float ncv  = sigm((mid+est)*64.f);
      a_c = clampf((pcv-ncv+1e-5f)/(pcv+1e-5f), 0.f, 1.f);
      qv  = 1.f - a_c + 1e-7f;
    }
    // exclusive cumprod of qv over lanes 0..62 (shuffle scan)
    float p = qv;
    #pragma unroll
    for (int off = 1; off < 64; off <<= 1){
      float t = __shfl_up(p, off);
      if (lane >= off) p *= t;
    }
    float ec = __shfl_up(p, 1);
    if (lane == 0) ec = 1.f;
    float wv = (lane < 63) ? (a_c*ec + 1e-5f) : 0.f;   // w_c + 1e-5
    float tot = wv;
    #pragma unroll
    for (int off = 32; off > 0; off >>= 1) tot += __shfl_xor(tot, off);
    float cs = wv;                                      // inclusive cumsum
    #pragma unroll
    for (int off = 1; off < 64; off <<= 1){
      float t = __shfl_up(cs, off);
      if (lane >= off) cs += t;
    }
    if (lane == 0)  s_cdf[rs][0] = 0.f;
    if (lane < 63)  s_cdf[rs][lane+1] = cs / tot;
  }
  __syncthreads();

  // ---- sample_pdf: searchsorted(side='right') + lerp ----
  if (wir == 0){
    float u = ((float)lane + 0.5f) * (1.f/64.f);
    int lo = 0, hi = 64;
    while (lo < hi){
      int m = (lo+hi) >> 1;
      if (s_cdf[rs][m] <= u) lo = m+1; else hi = m;
    }
    int below = lo - 1;                // lo >= 1 since cdf[0]=0 <= u
    int above = lo < 63 ? lo : 63;
    float cb = s_cdf[rs][below], ca = s_cdf[rs][above];
    float bb = s_z[rs][below],   ba = s_z[rs][above];
    float den = ca - cb; if (den < 1e-5f) den = 1.f;
    float tt = (u - cb)/den;
    s_newz[rs][lane] = bb + tt*(ba - bb);
  }
  __syncthreads();

  // ---- parallel merge of two sorted 64-lists (rank via binary search) ----
  {
    float v; int pos;
    if (lt < 64){
      v = s_z[rs][lt];
      int lo = 0, hi = 64;
      while (lo < hi){ int m=(lo+hi)>>1; if (s_newz[rs][m] < v) lo = m+1; else hi = m; }
      pos = lt + lo;
    } else {
      int jj = lt - 64;
      v = s_newz[rs][jj];
      int lo = 0, hi = 64;
      while (lo < hi){ int m=(lo+hi)>>1; if (s_z[rs][m] <= v) lo = m+1; else hi = m; }
      pos = jj + lo;
    }
    s_zall[rs][pos] = v;
  }
  __syncthreads();

  // ---- fine pass: thread lt = fine sample ----
  float zc = s_zall[rs][lt];
  float zn = s_zall[rs][lt < 127 ? lt+1 : 127];
  float delta = (lt < 127) ? (zn - zc) : sd;
  float zm    = (lt < 127) ? (zc + 0.5f*delta) : zc;
  float px = clampf(ox + dx*zm, -1.f, 1.f);
  float py = clampf(oy + dy*zm, -1.f, 1.f);
  float pz = clampf(oz + dz*zm, -1.f, 1.f);

  // full SDF net: out[0..64] in fa (float4 x17, padded to 68)
  float4 fa[17];
  #pragma unroll
  for (int c = 0; c < 17; ++c) fa[c] = sb2p[c];
  for (int j0 = 0; j0 < 64; j0 += 8){
    float hv[8];
    #pragma unroll
    for (int jj = 0; jj < 8; ++jj){
      float4 w = sW1p[j0+jj];
      hv[jj] = fmaxf(px*w.x + py*w.y + pz*w.z + w.w, 0.f);
    }
    #pragma unroll
    for (int jj = 0; jj < 8; ++jj){
      #pragma unroll
      for (int c = 0; c < 17; ++c){
        float4 w = sW2v4[(j0+jj)*17 + c];
        fa[c].x += hv[jj]*w.x;
        fa[c].y += hv[jj]*w.y;
        fa[c].z += hv[jj]*w.z;
        fa[c].w += hv[jj]*w.w;
      }
    }
  }
  float sdfv = fa[0].x;

  // 6-point finite-difference gradient (shares LDS weight reads across the 6 evals)
  float a0=b20,a1=b20,a2=b20,a3=b20,a4=b20,a5=b20;
  #pragma unroll 4
  for (int j = 0; j < 64; ++j){
    float4 w  = sW1p[j];
    float w2  = sw2c0[j];
    float base = px*w.x + py*w.y + pz*w.z + w.w;
    float ex = 0.005f*w.x, ey = 0.005f*w.y, ez = 0.005f*w.z;
    a0 += fmaxf(base+ex, 0.f)*w2;
    a1 += fmaxf(base-ex, 0.f)*w2;
    a2 += fmaxf(base+ey, 0.f)*w2;
    a3 += fmaxf(base-ey, 0.f)*w2;
    a4 += fmaxf(base+ez, 0.f)*w2;
    a5 += fmaxf(base-ez, 0.f)*w2;
  }
  float gx = (a0-a1)/0.01f, gy = (a2-a3)/0.01f, gz = (a4-a5)/0.01f;
  float gn = 1e-5f + sqrtf(gx*gx + gy*gy + gz*gz);
  float nx = gx/gn, ny = gy/gn, nz = gz/gn;

  // color net: cin = [pt, dir, normal, feat(out[1..64])] (73, padded to 76)
  float cin[76];
  cin[0]=px; cin[1]=py; cin[2]=pz;
  cin[3]=dx; cin[4]=dy; cin[5]=dz;
  cin[6]=nx; cin[7]=ny; cin[8]=nz;
  #pragma unroll
  for (int c = 0; c < 17; ++c){
    #pragma unroll
    for (int e = 0; e < 4; ++e){
      int k = 4*c + e;                 // out index
      if (k >= 1 && k <= 64) cin[8+k] = f4get(fa[c], e);
    }
  }
  cin[73]=0.f; cin[74]=0.f; cin[75]=0.f;
  float c0=0.f, c1=0.f, c2=0.f;
  for (int j = 0; j < 64; ++j){
    float acc = sbc1[j];
    #pragma unroll
    for (int c = 0; c < 19; ++c){
      float4 w = sWc1T[j*19 + c];
      acc += cin[4*c]*w.x + cin[4*c+1]*w.y + cin[4*c+2]*w.z + cin[4*c+3]*w.w;
    }
    float hcv = fmaxf(acc, 0.f);
    float4 w2 = sWc2p[j];
    c0 += hcv*w2.x; c1 += hcv*w2.y; c2 += hcv*w2.z;
  }
  c0 = sigm(c0 + bc2[0]);
  c1 = sigm(c1 + bc2[1]);
  c2 = sigm(c2 + bc2[2]);

  // NeuS alpha
  const float inv_s = expf(10.f * inv_s_p[0]);
  float tcos = dx*nx + dy*ny + dz*nz;
  float aarg = -100.f * tcos;
  float spv  = (aarg > 0.f) ? (aarg + log1pf(expf(-aarg))) : log1pf(expf(aarg));
  float iter_cos = -(spv / 100.f);
  float est = iter_cos * delta * 0.5f;
  float pcv = sigm((sdfv - est)*inv_s);
  float ncv = sigm((sdfv + est)*inv_s);
  float alpha = clampf((pcv - ncv + 1e-5f)/(pcv + 1e-5f), 0.f, 1.f);

  // transmittance weights over 128 samples (2-wave multiplicative scan) + composite
  float qv = 1.f - alpha + 1e-7f;
  float p = qv;
  #pragma unroll
  for (int off = 1; off < 64; off <<= 1){
    float t = __shfl_up(p, off);
    if (lane >= off) p *= t;
  }
  if (lane == 63) s_wtot[rs][wir] = p;
  __syncthreads();
  float excl = __shfl_up(p, 1);
  if (lane == 0) excl = 1.f;
  if (wir == 1) excl *= s_wtot[rs][0];
  float w  = alpha * excl;
  float r0 = w, r1 = w*c0, r2 = w*c1, r3 = w*c2;
  #pragma unroll
  for (int off = 32; off > 0; off >>= 1){
    r0 += __shfl_xor(r0, off);
    r1 += __shfl_xor(r1, off);
    r2 += __shfl_xor(r2, off);
    r3 += __shfl_xor(r3, off);
  }
  if (lane == 0){
    s_red[rs][wir][0]=r0; s_red[rs][wir][1]=r1; s_red[rs][wir][2]=r2; s_red[rs][wir][3]=r3;
  }
  __syncthreads();
  if (lt == 0){
    float wsum = s_red[rs][0][0] + s_red[rs][1][0];
    float bg = 1.f - wsum;
    out[ray*3+0] = s_red[rs][0][1] + s_red[rs][1][1] + bg;
    out[ray*3+1] = s_red[rs][0][2] + s_red[rs][1][2] + bg;
    out[ray*3+2] = s_red[rs][0][3] + s_red[rs][1][3] + bg;
  }
}

extern "C" void kernel_launch(void* const* d_in, const int* in_sizes, int n_in,
                              void* d_out, int out_size, void* d_ws, size_t ws_size,
                              hipStream_t stream)
{
  const float* rays_o = (const float*)d_in[0];
  const float* rays_d = (const float*)d_in[1];
  const float* W1  = (const float*)d_in[2];
  const float* b1  = (const float*)d_in[3];
  const float* W2  = (const float*)d_in[4];
  const float* b2  = (const float*)d_in[5];
  const float* Wc1 = (const float*)d_in[6];
  const float* bc1 = (const float*)d_in[7];
  const float* Wc2 = (const float*)d_in[8];
  const float* bc2 = (const float*)d_in[9];
  const float* inv_s = (const float*)d_in[10];
  float* out = (float*)d_out;

  const int R = in_sizes[0] / 3;               // 4096 rays
  dim3 grid(R / RAYS_PER_BLOCK), block(256);
  neus_render<<<grid, block, 0, stream>>>(rays_o, rays_d, W1, b1, W2, b2,
                                          Wc1, bc1, Wc2, bc2, inv_s, out);
}

// Round 2
// 256.005 us; speedup vs baseline: 1.3396x; 1.3396x over previous
//
#include <hip/hip_runtime.h>
#include <cmath>

#define RAYS_PER_BLOCK 2

// ---- packed-weight layout in d_ws (float offsets) ----
#define OFF_W1    0        // 64 x float4: {W1[0][j],W1[1][j],W1[2][j],b1[j]}
#define OFF_W2    256      // 64 x 17 x float4: W2 row j, cols padded 65->68
#define OFF_B2    4608     // 17 x float4: b2 padded 65->68
#define OFF_W2C0  4676     // 64: W2[:,0]
#define OFF_WC1T  4740     // 64 x 19 x float4: Wc1 transposed, 73->76
#define OFF_WC2   9604     // 64 x float4: {Wc2[j][0..2],0}
#define OFF_BC1   9860     // 64
#define OFF_BC2   9924     // 4
#define WS_FLOATS 9928

__device__ __forceinline__ float sigm(float x){ return 1.0f/(1.0f + expf(-x)); }
__device__ __forceinline__ float clampf(float x, float lo, float hi){ return fminf(fmaxf(x, lo), hi); }
__device__ __forceinline__ float f4get(const float4 v, int e){
  return e==0 ? v.x : (e==1 ? v.y : (e==2 ? v.z : v.w));
}

// Pack/pad/transpose weights into ws so the render kernel's weight reads are
// aligned float4 at wave-uniform affine indices (-> s_load scalarization).
__global__ void prep_weights(const float* __restrict__ W1, const float* __restrict__ b1,
                             const float* __restrict__ W2, const float* __restrict__ b2,
                             const float* __restrict__ Wc1, const float* __restrict__ bc1,
                             const float* __restrict__ Wc2, const float* __restrict__ bc2,
                             float* __restrict__ ws)
{
  const int tid = threadIdx.x;
  for (int i = tid; i < 64; i += 256){
    ws[OFF_W1 + 4*i + 0] = W1[i];
    ws[OFF_W1 + 4*i + 1] = W1[64+i];
    ws[OFF_W1 + 4*i + 2] = W1[128+i];
    ws[OFF_W1 + 4*i + 3] = b1[i];
    ws[OFF_W2C0 + i] = W2[i*65];
    ws[OFF_BC1 + i]  = bc1[i];
    ws[OFF_WC2 + 4*i + 0] = Wc2[i*3+0];
    ws[OFF_WC2 + 4*i + 1] = Wc2[i*3+1];
    ws[OFF_WC2 + 4*i + 2] = Wc2[i*3+2];
    ws[OFF_WC2 + 4*i + 3] = 0.f;
  }
  for (int i = tid; i < 64*68; i += 256){
    int j = i/68, k = i - j*68;
    ws[OFF_W2 + i] = (k < 65) ? W2[j*65+k] : 0.f;
  }
  for (int i = tid; i < 68; i += 256) ws[OFF_B2 + i] = (i < 65) ? b2[i] : 0.f;
  for (int i = tid; i < 64*76; i += 256){
    int j = i/76, c = i - j*76;
    ws[OFF_WC1T + i] = (c < 73) ? Wc1[c*64 + j] : 0.f;
  }
  if (tid < 4) ws[OFF_BC2 + tid] = (tid < 3) ? bc2[tid] : 0.f;
}

// One block = 2 rays x 128 threads; thread lt = fine sample.
__global__ __launch_bounds__(256)
void neus_render(const float* __restrict__ rays_o, const float* __restrict__ rays_d,
                 const float* __restrict__ inv_s_p, const float* __restrict__ ws,
                 float* __restrict__ out)
{
  __shared__ float  s_z[RAYS_PER_BLOCK][64];     // coarse z (sorted)
  __shared__ float  s_cdf[RAYS_PER_BLOCK][64];   // sample_pdf cdf
  __shared__ float  s_newz[RAYS_PER_BLOCK][64];  // importance samples (sorted)
  __shared__ float  s_zall[RAYS_PER_BLOCK][128]; // merged sorted z
  __shared__ float  s_red[RAYS_PER_BLOCK][2][4];
  __shared__ float  s_wtot[RAYS_PER_BLOCK][2];

  const int tid  = threadIdx.x;
  const int rs   = tid >> 7;
  const int lt   = tid & 127;
  const int lane = tid & 63;
  const int wir  = (tid >> 6) & 1;
  const int ray  = blockIdx.x * RAYS_PER_BLOCK + rs;

  const float4* __restrict__ pW1   = (const float4*)(ws + OFF_W1);
  const float4* __restrict__ pW2   = (const float4*)(ws + OFF_W2);
  const float4* __restrict__ pB2   = (const float4*)(ws + OFF_B2);
  const float*  __restrict__ pw2c0 = ws + OFF_W2C0;
  const float4* __restrict__ pWc1T = (const float4*)(ws + OFF_WC1T);
  const float4* __restrict__ pWc2  = (const float4*)(ws + OFF_WC2);
  const float*  __restrict__ pbc1  = ws + OFF_BC1;
  const float*  __restrict__ pbc2  = ws + OFF_BC2;
  const float b20 = ws[OFF_B2];

  // ---- per-ray setup ----
  float ox = rays_o[ray*3], oy = rays_o[ray*3+1], oz = rays_o[ray*3+2];
  float dx = rays_d[ray*3], dy = rays_d[ray*3+1], dz = rays_d[ray*3+2];
  float tnx = (-1.f-ox)/(dx+1e-15f), tfx = (1.f-ox)/(dx+1e-15f);
  float tny = (-1.f-oy)/(dy+1e-15f), tfy = (1.f-oy)/(dy+1e-15f);
  float tnz = (-1.f-oz)/(dz+1e-15f), tfz = (1.f-oz)/(dz+1e-15f);
  float nearv = fmaxf(fmaxf(fminf(tnx,tfx), fminf(tny,tfy)), fminf(tnz,tfz));
  float farv  = fminf(fminf(fmaxf(tnx,tfx), fmaxf(tny,tfy)), fmaxf(tnz,tfz));
  nearv = fmaxf(nearv, 0.05f);
  const float sd = (farv - nearv) * (1.f/64.f);

  // ---- coarse pass: wave 0 of each ray (lane = coarse sample) ----
  if (wir == 0){
    float zt = nearv + (farv-nearv) * ((float)lane * (1.f/63.f));
    float px = clampf(ox + dx*zt, -1.f, 1.f);
    float py = clampf(oy + dy*zt, -1.f, 1.f);
    float pz = clampf(oz + dz*zt, -1.f, 1.f);
    float acc = b20;
    #pragma unroll 8
    for (int j = 0; j < 64; ++j){
      float4 w = pW1[j];
      acc += fmaxf(px*w.x + py*w.y + pz*w.z + w.w, 0.f) * pw2c0[j];
    }
    s_z[rs][lane] = zt;
    float s1  = __shfl_down(acc, 1);
    float zt1 = nearv + (farv-nearv) * ((float)(lane+1) * (1.f/63.f));
    float a_c = 0.f, qv = 1.f;
    if (lane < 63){
      float dc   = zt1 - zt;
      float mid  = 0.5f*(acc + s1);
      float cosv = clampf((s1-acc)/(dc+1e-5f), -1000.f, 0.f);
      float est  = cosv*dc*0.5f;
      float pcv  = sigm((mid-est)*64.f);
      float ncv  = sigm((mid+est)*64.f);
      a_c = clampf((pcv-ncv+1e-5f)/(pcv+1e-5f), 0.f, 1.f);
      qv  = 1.f - a_c + 1e-7f;
    }
    float p = qv;
    #pragma unroll
    for (int off = 1; off < 64; off <<= 1){
      float t = __shfl_up(p, off);
      if (lane >= off) p *= t;
    }
    float ec = __shfl_up(p, 1);
    if (lane == 0) ec = 1.f;
    float wv = (lane < 63) ? (a_c*ec + 1e-5f) : 0.f;
    float tot = wv;
    #pragma unroll
    for (int off = 32; off > 0; off >>= 1) tot += __shfl_xor(tot, off);
    float cs = wv;
    #pragma unroll
    for (int off = 1; off < 64; off <<= 1){
      float t = __shfl_up(cs, off);
      if (lane >= off) cs += t;
    }
    if (lane == 0)  s_cdf[rs][0] = 0.f;
    if (lane < 63)  s_cdf[rs][lane+1] = cs / tot;
  }
  __syncthreads();

  // ---- sample_pdf (searchsorted right + lerp) ----
  if (wir == 0){
    float u = ((float)lane + 0.5f) * (1.f/64.f);
    int lo = 0, hi = 64;
    while (lo < hi){
      int m = (lo+hi) >> 1;
      if (s_cdf[rs][m] <= u) lo = m+1; else hi = m;
    }
    int below = lo - 1;
    int above = lo < 63 ? lo : 63;
    float cb = s_cdf[rs][below], ca = s_cdf[rs][above];
    float bb = s_z[rs][below],   ba = s_z[rs][above];
    float den = ca - cb; if (den < 1e-5f) den = 1.f;
    float tt = (u - cb)/den;
    s_newz[rs][lane] = bb + tt*(ba - bb);
  }
  __syncthreads();

  // ---- parallel merge of two sorted 64-lists ----
  {
    float v; int pos;
    if (lt < 64){
      v = s_z[rs][lt];
      int lo = 0, hi = 64;
      while (lo < hi){ int m=(lo+hi)>>1; if (s_newz[rs][m] < v) lo = m+1; else hi = m; }
      pos = lt + lo;
    } else {
      int jj = lt - 64;
      v = s_newz[rs][jj];
      int lo = 0, hi = 64;
      while (lo < hi){ int m=(lo+hi)>>1; if (s_z[rs][m] <= v) lo = m+1; else hi = m; }
      pos = jj + lo;
    }
    s_zall[rs][pos] = v;
  }
  __syncthreads();

  // ---- fine pass (uniform control flow: weight reads scalarize) ----
  float zc = s_zall[rs][lt];
  float zn = s_zall[rs][lt < 127 ? lt+1 : 127];
  float delta = (lt < 127) ? (zn - zc) : sd;
  float zm    = (lt < 127) ? (zc + 0.5f*delta) : zc;
  float px = clampf(ox + dx*zm, -1.f, 1.f);
  float py = clampf(oy + dy*zm, -1.f, 1.f);
  float pz = clampf(oz + dz*zm, -1.f, 1.f);

  // SDF net (65 outputs) fused with 6-point FD gradient on col 0
  float4 fa[17];
  #pragma unroll
  for (int c = 0; c < 17; ++c) fa[c] = pB2[c];
  float a0=b20,a1=b20,a2=b20,a3=b20,a4=b20,a5=b20;
  #pragma unroll 2
  for (int j = 0; j < 64; ++j){
    float4 w  = pW1[j];
    float w2  = pw2c0[j];
    float base = px*w.x + py*w.y + pz*w.z + w.w;
    float hv = fmaxf(base, 0.f);
    float ex = 0.005f*w.x, ey = 0.005f*w.y, ez = 0.005f*w.z;
    a0 += fmaxf(base+ex, 0.f)*w2;
    a1 += fmaxf(base-ex, 0.f)*w2;
    a2 += fmaxf(base+ey, 0.f)*w2;
    a3 += fmaxf(base-ey, 0.f)*w2;
    a4 += fmaxf(base+ez, 0.f)*w2;
    a5 += fmaxf(base-ez, 0.f)*w2;
    const float4* row = pW2 + j*17;
    #pragma unroll
    for (int c = 0; c < 17; ++c){
      float4 ww = row[c];
      fa[c].x += hv*ww.x;
      fa[c].y += hv*ww.y;
      fa[c].z += hv*ww.z;
      fa[c].w += hv*ww.w;
    }
  }
  float sdfv = fa[0].x;
  float gx = (a0-a1)*100.f, gy = (a2-a3)*100.f, gz = (a4-a5)*100.f;
  float gn = 1e-5f + sqrtf(gx*gx + gy*gy + gz*gz);
  float nx = gx/gn, ny = gy/gn, nz = gz/gn;

  // color net: cin = [pt, dir, normal, feat] (73 -> 76)
  float cin[76];
  cin[0]=px; cin[1]=py; cin[2]=pz;
  cin[3]=dx; cin[4]=dy; cin[5]=dz;
  cin[6]=nx; cin[7]=ny; cin[8]=nz;
  #pragma unroll
  for (int c = 0; c < 17; ++c){
    #pragma unroll
    for (int e = 0; e < 4; ++e){
      int k = 4*c + e;
      if (k >= 1 && k <= 64) cin[8+k] = f4get(fa[c], e);
    }
  }
  cin[73]=0.f; cin[74]=0.f; cin[75]=0.f;
  float c0=0.f, c1=0.f, c2=0.f;
  #pragma unroll 2
  for (int j = 0; j < 64; ++j){
    float acc = pbc1[j];
    const float4* row = pWc1T + j*19;
    #pragma unroll
    for (int c = 0; c < 19; ++c){
      float4 w = row[c];
      acc += cin[4*c]*w.x + cin[4*c+1]*w.y + cin[4*c+2]*w.z + cin[4*c+3]*w.w;
    }
    float hcv = fmaxf(acc, 0.f);
    float4 w2 = pWc2[j];
    c0 += hcv*w2.x; c1 += hcv*w2.y; c2 += hcv*w2.z;
  }
  c0 = sigm(c0 + pbc2[0]);
  c1 = sigm(c1 + pbc2[1]);
  c2 = sigm(c2 + pbc2[2]);

  // NeuS alpha
  const float inv_s = expf(10.f * inv_s_p[0]);
  float tcos = dx*nx + dy*ny + dz*nz;
  float aarg = -100.f * tcos;
  float spv  = (aarg > 0.f) ? (aarg + log1pf(expf(-aarg))) : log1pf(expf(aarg));
  float iter_cos = -(spv * 0.01f);
  float est = iter_cos * delta * 0.5f;
  float pcv = sigm((sdfv - est)*inv_s);
  float ncv = sigm((sdfv + est)*inv_s);
  float alpha = clampf((pcv - ncv + 1e-5f)/(pcv + 1e-5f), 0.f, 1.f);

  // transmittance scan over 128 samples (2 waves) + composite
  float qv = 1.f - alpha + 1e-7f;
  float p = qv;
  #pragma unroll
  for (int off = 1; off < 64; off <<= 1){
    float t = __shfl_up(p, off);
    if (lane >= off) p *= t;
  }
  if (lane == 63) s_wtot[rs][wir] = p;
  __syncthreads();
  float excl = __shfl_up(p, 1);
  if (lane == 0) excl = 1.f;
  if (wir == 1) excl *= s_wtot[rs][0];
  float w  = alpha * excl;
  float r0 = w, r1 = w*c0, r2 = w*c1, r3 = w*c2;
  #pragma unroll
  for (int off = 32; off > 0; off >>= 1){
    r0 += __shfl_xor(r0, off);
    r1 += __shfl_xor(r1, off);
    r2 += __shfl_xor(r2, off);
    r3 += __shfl_xor(r3, off);
  }
  if (lane == 0){
    s_red[rs][wir][0]=r0; s_red[rs][wir][1]=r1; s_red[rs][wir][2]=r2; s_red[rs][wir][3]=r3;
  }
  __syncthreads();
  if (lt == 0){
    float wsum = s_red[rs][0][0] + s_red[rs][1][0];
    float bg = 1.f - wsum;
    out[ray*3+0] = s_red[rs][0][1] + s_red[rs][1][1] + bg;
    out[ray*3+1] = s_red[rs][0][2] + s_red[rs][1][2] + bg;
    out[ray*3+2] = s_red[rs][0][3] + s_red[rs][1][3] + bg;
  }
}

extern "C" void kernel_launch(void* const* d_in, const int* in_sizes, int n_in,
                              void* d_out, int out_size, void* d_ws, size_t ws_size,
                              hipStream_t stream)
{
  const float* rays_o = (const float*)d_in[0];
  const float* rays_d = (const float*)d_in[1];
  const float* W1  = (const float*)d_in[2];
  const float* b1  = (const float*)d_in[3];
  const float* W2  = (const float*)d_in[4];
  const float* b2  = (const float*)d_in[5];
  const float* Wc1 = (const float*)d_in[6];
  const float* bc1 = (const float*)d_in[7];
  const float* Wc2 = (const float*)d_in[8];
  const float* bc2 = (const float*)d_in[9];
  const float* inv_s = (const float*)d_in[10];
  float* out = (float*)d_out;
  float* ws  = (float*)d_ws;

  prep_weights<<<1, 256, 0, stream>>>(W1, b1, W2, b2, Wc1, bc1, Wc2, bc2, ws);

  const int R = in_sizes[0] / 3;               // 4096 rays
  dim3 grid(R / RAYS_PER_BLOCK), block(256);
  neus_render<<<grid, block, 0, stream>>>(rays_o, rays_d, inv_s, ws, out);
}

// Round 3
// 182.973 us; speedup vs baseline: 1.8744x; 1.3991x over previous
//
#include <hip/hip_runtime.h>
#include <cmath>

#define RAYS_PER_BLOCK 2

// ---- packed-weight layout in d_ws (float offsets) ----
#define OFF_W1    0      // 64 x float4 {W1[0][j],W1[1][j],W1[2][j],b1[j]}
#define OFF_W1E   256    // 64 x float4 {eps*W1x, eps*W1y, eps*W1z, W2[j][0]}
#define OFF_M     512    // 64x64: M[h][j] = sum_k W2[h][1+k]*Wc1[9+k][j]
#define OFF_CROWS 4608   // 9x64: Wc1 rows 0..8 (row i contiguous over j)
#define OFF_CB    5184   // 64: bc1[j] + sum_k b2[1+k]*Wc1[9+k][j]
#define OFF_WC2   5248   // 64 x float4 {Wc2[j][0..2], 0}
#define OFF_BC2   5504   // {bc2[0],bc2[1],bc2[2], b2[0]}
#define WS_FLOATS 5508

__device__ __forceinline__ float sigm(float x){ return 1.0f/(1.0f + expf(-x)); }
__device__ __forceinline__ float clampf(float x, float lo, float hi){ return fminf(fmaxf(x, lo), hi); }
__device__ __forceinline__ float f4get(const float4 v, int e){
  return e==0 ? v.x : (e==1 ? v.y : (e==2 ? v.z : v.w));
}

// Parallel prep: pack/pad/compose weights into ws. All tasks independent.
__global__ void prep_weights(const float* __restrict__ W1, const float* __restrict__ b1,
                             const float* __restrict__ W2, const float* __restrict__ b2,
                             const float* __restrict__ Wc1, const float* __restrict__ bc1,
                             const float* __restrict__ Wc2, const float* __restrict__ bc2,
                             float* __restrict__ ws)
{
  int g = blockIdx.x * blockDim.x + threadIdx.x;
  if (g < 4096){                       // M[h][j], 64-MAC dot each
    int h = g >> 6, j = g & 63;
    float acc = 0.f;
    for (int k = 0; k < 64; ++k) acc += W2[h*65 + 1 + k] * Wc1[(9+k)*64 + j];
    ws[OFF_M + g] = acc;
  } else if (g < 4096 + 576){          // Wc1 rows 0..8 (straight copy)
    int i = g - 4096;
    ws[OFF_CROWS + i] = Wc1[i];
  } else if (g < 4096 + 576 + 64){     // cb[j]
    int j = g - (4096 + 576);
    float acc = bc1[j];
    for (int k = 0; k < 64; ++k) acc += b2[1+k] * Wc1[(9+k)*64 + j];
    ws[OFF_CB + j] = acc;
  } else if (g < 4096 + 576 + 128){    // W1 pack
    int j = g - (4096 + 576 + 64);
    ws[OFF_W1 + 4*j + 0] = W1[j];
    ws[OFF_W1 + 4*j + 1] = W1[64+j];
    ws[OFF_W1 + 4*j + 2] = W1[128+j];
    ws[OFF_W1 + 4*j + 3] = b1[j];
  } else if (g < 4096 + 576 + 192){    // W1E pack
    int j = g - (4096 + 576 + 128);
    ws[OFF_W1E + 4*j + 0] = 0.005f * W1[j];
    ws[OFF_W1E + 4*j + 1] = 0.005f * W1[64+j];
    ws[OFF_W1E + 4*j + 2] = 0.005f * W1[128+j];
    ws[OFF_W1E + 4*j + 3] = W2[j*65];
  } else if (g < 4096 + 576 + 256){    // Wc2 pack
    int j = g - (4096 + 576 + 192);
    ws[OFF_WC2 + 4*j + 0] = Wc2[j*3+0];
    ws[OFF_WC2 + 4*j + 1] = Wc2[j*3+1];
    ws[OFF_WC2 + 4*j + 2] = Wc2[j*3+2];
    ws[OFF_WC2 + 4*j + 3] = 0.f;
  } else if (g < 4096 + 576 + 260){    // bc2 + b2[0]
    int j = g - (4096 + 576 + 256);
    ws[OFF_BC2 + j] = (j < 3) ? bc2[j] : b2[0];
  }
}

// One block = 2 rays x 128 threads; thread lt = fine sample.
__global__ __launch_bounds__(256)
void neus_render(const float* __restrict__ rays_o, const float* __restrict__ rays_d,
                 const float* __restrict__ inv_s_p, const float* __restrict__ ws,
                 float* __restrict__ out)
{
  __shared__ float  s_z[RAYS_PER_BLOCK][64];
  __shared__ float  s_cdf[RAYS_PER_BLOCK][64];
  __shared__ float  s_newz[RAYS_PER_BLOCK][64];
  __shared__ float  s_zall[RAYS_PER_BLOCK][128];
  __shared__ float  s_red[RAYS_PER_BLOCK][2][4];
  __shared__ float  s_wtot[RAYS_PER_BLOCK][2];

  const int tid  = threadIdx.x;
  const int rs   = tid >> 7;
  const int lt   = tid & 127;
  const int lane = tid & 63;
  const int wir  = (tid >> 6) & 1;
  const int ray  = blockIdx.x * RAYS_PER_BLOCK + rs;

  const float4* __restrict__ pW1  = (const float4*)(ws + OFF_W1);
  const float4* __restrict__ pW1E = (const float4*)(ws + OFF_W1E);
  const float4* __restrict__ pM   = (const float4*)(ws + OFF_M);
  const float4* __restrict__ prow = (const float4*)(ws + OFF_CROWS);
  const float4* __restrict__ pCB  = (const float4*)(ws + OFF_CB);
  const float4* __restrict__ pWc2 = (const float4*)(ws + OFF_WC2);
  const float*  __restrict__ pbc2 = ws + OFF_BC2;
  const float b20 = pbc2[3];

  // ---- per-ray setup ----
  float ox = rays_o[ray*3], oy = rays_o[ray*3+1], oz = rays_o[ray*3+2];
  float dx = rays_d[ray*3], dy = rays_d[ray*3+1], dz = rays_d[ray*3+2];
  float tnx = (-1.f-ox)/(dx+1e-15f), tfx = (1.f-ox)/(dx+1e-15f);
  float tny = (-1.f-oy)/(dy+1e-15f), tfy = (1.f-oy)/(dy+1e-15f);
  float tnz = (-1.f-oz)/(dz+1e-15f), tfz = (1.f-oz)/(dz+1e-15f);
  float nearv = fmaxf(fmaxf(fminf(tnx,tfx), fminf(tny,tfy)), fminf(tnz,tfz));
  float farv  = fminf(fminf(fmaxf(tnx,tfx), fmaxf(tny,tfy)), fmaxf(tnz,tfz));
  nearv = fmaxf(nearv, 0.05f);
  const float sd = (farv - nearv) * (1.f/64.f);

  // ---- coarse pass: wave 0 of each ray (lane = coarse sample) ----
  if (wir == 0){
    float zt = nearv + (farv-nearv) * ((float)lane * (1.f/63.f));
    float px = clampf(ox + dx*zt, -1.f, 1.f);
    float py = clampf(oy + dy*zt, -1.f, 1.f);
    float pz = clampf(oz + dz*zt, -1.f, 1.f);
    float acc = b20;
    #pragma unroll 8
    for (int j = 0; j < 64; ++j){
      float4 w = pW1[j];
      acc += fmaxf(px*w.x + py*w.y + pz*w.z + w.w, 0.f) * ws[OFF_W1E + 4*j + 3];
    }
    s_z[rs][lane] = zt;
    float s1  = __shfl_down(acc, 1);
    float zt1 = nearv + (farv-nearv) * ((float)(lane+1) * (1.f/63.f));
    float a_c = 0.f, qv = 1.f;
    if (lane < 63){
      float dc   = zt1 - zt;
      float mid  = 0.5f*(acc + s1);
      float cosv = clampf((s1-acc)/(dc+1e-5f), -1000.f, 0.f);
      float est  = cosv*dc*0.5f;
      float pcv  = sigm((mid-est)*64.f);
      float ncv  = sigm((mid+est)*64.f);
      a_c = clampf((pcv-ncv+1e-5f)/(pcv+1e-5f), 0.f, 1.f);
      qv  = 1.f - a_c + 1e-7f;
    }
    float p = qv;
    #pragma unroll
    for (int off = 1; off < 64; off <<= 1){
      float t = __shfl_up(p, off);
      if (lane >= off) p *= t;
    }
    float ec = __shfl_up(p, 1);
    if (lane == 0) ec = 1.f;
    float wv = (lane < 63) ? (a_c*ec + 1e-5f) : 0.f;
    float tot = wv;
    #pragma unroll
    for (int off = 32; off > 0; off >>= 1) tot += __shfl_xor(tot, off);
    float cs = wv;
    #pragma unroll
    for (int off = 1; off < 64; off <<= 1){
      float t = __shfl_up(cs, off);
      if (lane >= off) cs += t;
    }
    if (lane == 0)  s_cdf[rs][0] = 0.f;
    if (lane < 63)  s_cdf[rs][lane+1] = cs / tot;
  }
  __syncthreads();

  // ---- sample_pdf (searchsorted right + lerp) ----
  if (wir == 0){
    float u = ((float)lane + 0.5f) * (1.f/64.f);
    int lo = 0, hi = 64;
    while (lo < hi){
      int m = (lo+hi) >> 1;
      if (s_cdf[rs][m] <= u) lo = m+1; else hi = m;
    }
    int below = lo - 1;
    int above = lo < 63 ? lo : 63;
    float cb = s_cdf[rs][below], ca = s_cdf[rs][above];
    float bb = s_z[rs][below],   ba = s_z[rs][above];
    float den = ca - cb; if (den < 1e-5f) den = 1.f;
    float tt = (u - cb)/den;
    s_newz[rs][lane] = bb + tt*(ba - bb);
  }
  __syncthreads();

  // ---- parallel merge of two sorted 64-lists ----
  {
    float v; int pos;
    if (lt < 64){
      v = s_z[rs][lt];
      int lo = 0, hi = 64;
      while (lo < hi){ int m=(lo+hi)>>1; if (s_newz[rs][m] < v) lo = m+1; else hi = m; }
      pos = lt + lo;
    } else {
      int jj = lt - 64;
      v = s_newz[rs][jj];
      int lo = 0, hi = 64;
      while (lo < hi){ int m=(lo+hi)>>1; if (s_z[rs][m] <= v) lo = m+1; else hi = m; }
      pos = jj + lo;
    }
    s_zall[rs][pos] = v;
  }
  __syncthreads();

  // ---- fine pass (uniform control flow -> weight reads scalarize) ----
  float zc = s_zall[rs][lt];
  float zn = s_zall[rs][lt < 127 ? lt+1 : 127];
  float delta = (lt < 127) ? (zn - zc) : sd;
  float zm    = (lt < 127) ? (zc + 0.5f*delta) : zc;
  float px = clampf(ox + dx*zm, -1.f, 1.f);
  float py = clampf(oy + dy*zm, -1.f, 1.f);
  float pz = clampf(oz + dz*zm, -1.f, 1.f);

  // color-hidden pre-activations, init = cb + pt/dir rows
  float4 cpre[16];
  #pragma unroll
  for (int c = 0; c < 16; ++c){
    float4 v  = pCB[c];
    float4 r0 = prow[ 0*16 + c], r1 = prow[ 1*16 + c], r2 = prow[ 2*16 + c];
    float4 r3 = prow[ 3*16 + c], r4 = prow[ 4*16 + c], r5 = prow[ 5*16 + c];
    v.x += px*r0.x + py*r1.x + pz*r2.x + dx*r3.x + dy*r4.x + dz*r5.x;
    v.y += px*r0.y + py*r1.y + pz*r2.y + dx*r3.y + dy*r4.y + dz*r5.y;
    v.z += px*r0.z + py*r1.z + pz*r2.z + dx*r3.z + dy*r4.z + dz*r5.z;
    v.w += px*r0.w + py*r1.w + pz*r2.w + dx*r3.w + dy*r4.w + dz*r5.w;
    cpre[c] = v;
  }

  // SDF col-0 + 6-point FD grad + rank-1 M accumulate into cpre
  float sa = b20;
  float a0=b20,a1=b20,a2=b20,a3=b20,a4=b20,a5=b20;
  #pragma unroll 4
  for (int j = 0; j < 64; ++j){
    float4 w = pW1[j];
    float4 e = pW1E[j];
    float base = fmaf(px, w.x, fmaf(py, w.y, fmaf(pz, w.z, w.w)));
    float hv = fmaxf(base, 0.f);
    sa = fmaf(hv, e.w, sa);
    a0 = fmaf(fmaxf(base+e.x, 0.f), e.w, a0);
    a1 = fmaf(fmaxf(base-e.x, 0.f), e.w, a1);
    a2 = fmaf(fmaxf(base+e.y, 0.f), e.w, a2);
    a3 = fmaf(fmaxf(base-e.y, 0.f), e.w, a3);
    a4 = fmaf(fmaxf(base+e.z, 0.f), e.w, a4);
    a5 = fmaf(fmaxf(base-e.z, 0.f), e.w, a5);
    const float4* mrow = pM + j*16;
    #pragma unroll
    for (int c = 0; c < 16; ++c){
      float4 m = mrow[c];
      cpre[c].x = fmaf(hv, m.x, cpre[c].x);
      cpre[c].y = fmaf(hv, m.y, cpre[c].y);
      cpre[c].z = fmaf(hv, m.z, cpre[c].z);
      cpre[c].w = fmaf(hv, m.w, cpre[c].w);
    }
  }
  float sdfv = sa;
  float gx = (a0-a1)*100.f, gy = (a2-a3)*100.f, gz = (a4-a5)*100.f;
  float gn = 1e-5f + sqrtf(gx*gx + gy*gy + gz*gz);
  float nx = gx/gn, ny = gy/gn, nz = gz/gn;

  // add normal rows, then color output
  float c0=0.f, c1=0.f, c2=0.f;
  #pragma unroll
  for (int c = 0; c < 16; ++c){
    float4 r6 = prow[6*16 + c], r7 = prow[7*16 + c], r8 = prow[8*16 + c];
    float4 v = cpre[c];
    v.x += nx*r6.x + ny*r7.x + nz*r8.x;
    v.y += nx*r6.y + ny*r7.y + nz*r8.y;
    v.z += nx*r6.z + ny*r7.z + nz*r8.z;
    v.w += nx*r6.w + ny*r7.w + nz*r8.w;
    #pragma unroll
    for (int e = 0; e < 4; ++e){
      float hcv = fmaxf(f4get(v, e), 0.f);
      float4 w2 = pWc2[c*4 + e];
      c0 = fmaf(hcv, w2.x, c0);
      c1 = fmaf(hcv, w2.y, c1);
      c2 = fmaf(hcv, w2.z, c2);
    }
  }
  c0 = sigm(c0 + pbc2[0]);
  c1 = sigm(c1 + pbc2[1]);
  c2 = sigm(c2 + pbc2[2]);

  // NeuS alpha
  const float inv_s = expf(10.f * inv_s_p[0]);
  float tcos = dx*nx + dy*ny + dz*nz;
  float aarg = -100.f * tcos;
  float spv  = (aarg > 0.f) ? (aarg + log1pf(expf(-aarg))) : log1pf(expf(aarg));
  float iter_cos = -(spv * 0.01f);
  float est = iter_cos * delta * 0.5f;
  float pcv = sigm((sdfv - est)*inv_s);
  float ncv = sigm((sdfv + est)*inv_s);
  float alpha = clampf((pcv - ncv + 1e-5f)/(pcv + 1e-5f), 0.f, 1.f);

  // transmittance scan over 128 samples (2 waves) + composite
  float qv = 1.f - alpha + 1e-7f;
  float p = qv;
  #pragma unroll
  for (int off = 1; off < 64; off <<= 1){
    float t = __shfl_up(p, off);
    if (lane >= off) p *= t;
  }
  if (lane == 63) s_wtot[rs][wir] = p;
  __syncthreads();
  float excl = __shfl_up(p, 1);
  if (lane == 0) excl = 1.f;
  if (wir == 1) excl *= s_wtot[rs][0];
  float w  = alpha * excl;
  float r0 = w, r1 = w*c0, r2 = w*c1, r3 = w*c2;
  #pragma unroll
  for (int off = 32; off > 0; off >>= 1){
    r0 += __shfl_xor(r0, off);
    r1 += __shfl_xor(r1, off);
    r2 += __shfl_xor(r2, off);
    r3 += __shfl_xor(r3, off);
  }
  if (lane == 0){
    s_red[rs][wir][0]=r0; s_red[rs][wir][1]=r1; s_red[rs][wir][2]=r2; s_red[rs][wir][3]=r3;
  }
  __syncthreads();
  if (lt == 0){
    float wsum = s_red[rs][0][0] + s_red[rs][1][0];
    float bg = 1.f - wsum;
    out[ray*3+0] = s_red[rs][0][1] + s_red[rs][1][1] + bg;
    out[ray*3+1] = s_red[rs][0][2] + s_red[rs][1][2] + bg;
    out[ray*3+2] = s_red[rs][0][3] + s_red[rs][1][3] + bg;
  }
}

extern "C" void kernel_launch(void* const* d_in, const int* in_sizes, int n_in,
                              void* d_out, int out_size, void* d_ws, size_t ws_size,
                              hipStream_t stream)
{
  const float* rays_o = (const float*)d_in[0];
  const float* rays_d = (const float*)d_in[1];
  const float* W1  = (const float*)d_in[2];
  const float* b1  = (const float*)d_in[3];
  const float* W2  = (const float*)d_in[4];
  const float* b2  = (const float*)d_in[5];
  const float* Wc1 = (const float*)d_in[6];
  const float* bc1 = (const float*)d_in[7];
  const float* Wc2 = (const float*)d_in[8];
  const float* bc2 = (const float*)d_in[9];
  const float* inv_s = (const float*)d_in[10];
  float* out = (float*)d_out;
  float* ws  = (float*)d_ws;

  prep_weights<<<20, 256, 0, stream>>>(W1, b1, W2, b2, Wc1, bc1, Wc2, bc2, ws);

  const int R = in_sizes[0] / 3;               // 4096 rays
  dim3 grid(R / RAYS_PER_BLOCK), block(256);
  neus_render<<<grid, block, 0, stream>>>(rays_o, rays_d, inv_s, ws, out);
}

// Round 4
// 145.805 us; speedup vs baseline: 2.3522x; 1.2549x over previous
//
#include <hip/hip_runtime.h>
#include <hip/hip_bf16.h>
#include <cmath>

#define RAYS_PER_BLOCK 2
#define KS 84   // aext row stride in ushorts (bank-decorrelated, 8B-aligned rows)

// ---- packed-weight layout in d_ws (float offsets) ----
#define OFF_W1    0      // 64 x float4 {W1[0][j],W1[1][j],W1[2][j],b1[j]}
#define OFF_W1E   256    // 64 x float4 {eps*W1x, eps*W1y, eps*W1z, W2[j][0]}
#define OFF_WC2   512    // 64 x float4 {Wc2[c][0..2], 0}
#define OFF_BC2   768    // {bc2[0],bc2[1],bc2[2], b2[0]}
#define OFF_AF    772    // 10 frags x 64 lanes x 8 bf16, A-operand-swizzled (16B/lane/frag)

typedef __attribute__((ext_vector_type(4))) short  short4v;
typedef __attribute__((ext_vector_type(8))) short  short8v;
typedef __attribute__((ext_vector_type(16))) float f32x16;

__device__ __forceinline__ float sigm(float x){ return 1.0f/(1.0f + expf(-x)); }
__device__ __forceinline__ float clampf(float x, float lo, float hi){ return fminf(fmaxf(x, lo), hi); }
__device__ __forceinline__ unsigned short f2bf(float x){
  __hip_bfloat16 h = __float2bfloat16(x);
  return *reinterpret_cast<unsigned short*>(&h);
}
__device__ __forceinline__ unsigned pk2(float a, float b){
  return (unsigned)f2bf(a) | ((unsigned)f2bf(b) << 16);
}
__device__ __forceinline__ short8v lds_load8(const unsigned short* p){
  short4v lo = *(const short4v*)p;
  short4v hi = *(const short4v*)(p + 4);
  short8v r;
  r[0]=lo[0]; r[1]=lo[1]; r[2]=lo[2]; r[3]=lo[3];
  r[4]=hi[0]; r[5]=hi[1]; r[6]=hi[2]; r[7]=hi[3];
  return r;
}

// A[c][k]: k<64 -> M[k][c]=sum_t W2[k][1+t]*Wc1[9+t][c]; k=64..72 -> Wc1[k-64][c];
// k=73 -> cb[c]=bc1[c]+sum_t b2[1+t]*Wc1[9+t][c]; k>=74 -> 0.
__global__ void prep_weights(const float* __restrict__ W1, const float* __restrict__ b1,
                             const float* __restrict__ W2, const float* __restrict__ b2,
                             const float* __restrict__ Wc1, const float* __restrict__ bc1,
                             const float* __restrict__ Wc2, const float* __restrict__ bc2,
                             float* __restrict__ ws)
{
  int g = blockIdx.x * blockDim.x + threadIdx.x;
  if (g < 640){                       // A-fragment swizzle: frag f=(mb*5+kk), lane ln
    int f = g >> 6, ln = g & 63;
    int mb = f / 5, kk = f - 5*mb;
    int c  = 32*mb + (ln & 31);
    int kbase = 16*kk + 8*(ln >> 5);
    unsigned short* dst = ((unsigned short*)(ws + OFF_AF)) + (size_t)g * 8;
    for (int j = 0; j < 8; ++j){
      int k = kbase + j;
      float v;
      if (k < 64){
        v = 0.f;
        for (int t = 0; t < 64; ++t) v += W2[k*65 + 1 + t] * Wc1[(9+t)*64 + c];
      } else if (k < 73){
        v = Wc1[(k-64)*64 + c];
      } else if (k == 73){
        v = bc1[c];
        for (int t = 0; t < 64; ++t) v += b2[1+t] * Wc1[(9+t)*64 + c];
      } else v = 0.f;
      dst[j] = f2bf(v);
    }
  } else if (g < 704){                // W1 pack
    int j = g - 640;
    ws[OFF_W1 + 4*j + 0] = W1[j];
    ws[OFF_W1 + 4*j + 1] = W1[64+j];
    ws[OFF_W1 + 4*j + 2] = W1[128+j];
    ws[OFF_W1 + 4*j + 3] = b1[j];
  } else if (g < 768){                // W1E pack
    int j = g - 704;
    ws[OFF_W1E + 4*j + 0] = 0.005f * W1[j];
    ws[OFF_W1E + 4*j + 1] = 0.005f * W1[64+j];
    ws[OFF_W1E + 4*j + 2] = 0.005f * W1[128+j];
    ws[OFF_W1E + 4*j + 3] = W2[j*65];
  } else if (g < 832){                // Wc2 pack
    int j = g - 768;
    ws[OFF_WC2 + 4*j + 0] = Wc2[j*3+0];
    ws[OFF_WC2 + 4*j + 1] = Wc2[j*3+1];
    ws[OFF_WC2 + 4*j + 2] = Wc2[j*3+2];
    ws[OFF_WC2 + 4*j + 3] = 0.f;
  } else if (g < 836){                // bc2 + b2[0]
    int j = g - 832;
    ws[OFF_BC2 + j] = (j < 3) ? bc2[j] : b2[0];
  }
}

// One block = 2 rays x 128 threads; thread lt = fine sample; wave = 64 samples.
__global__ __launch_bounds__(256)
void neus_render(const float* __restrict__ rays_o, const float* __restrict__ rays_d,
                 const float* __restrict__ inv_s_p, const float* __restrict__ ws,
                 float* __restrict__ out)
{
  __shared__ unsigned short s_aext[4][64*KS];   // per-wave activation rows (bf16)
  __shared__ float4 s_wc2[64];
  __shared__ float  s_z[RAYS_PER_BLOCK][64];
  __shared__ float  s_cdf[RAYS_PER_BLOCK][64];
  __shared__ float  s_newz[RAYS_PER_BLOCK][64];
  __shared__ float  s_zall[RAYS_PER_BLOCK][128];
  __shared__ float  s_red[RAYS_PER_BLOCK][2][4];
  __shared__ float  s_wtot[RAYS_PER_BLOCK][2];

  const int tid  = threadIdx.x;
  const int rs   = tid >> 7;
  const int lt   = tid & 127;
  const int lane = tid & 63;
  const int wir  = (tid >> 6) & 1;
  const int wv   = tid >> 6;
  const int ray  = blockIdx.x * RAYS_PER_BLOCK + rs;

  const float4* __restrict__ pW1  = (const float4*)(ws + OFF_W1);
  const float4* __restrict__ pW1E = (const float4*)(ws + OFF_W1E);
  const float*  __restrict__ pbc2 = ws + OFF_BC2;
  const float b20 = pbc2[3];

  if (tid < 64) s_wc2[tid] = ((const float4*)(ws + OFF_WC2))[tid];

  // ---- per-ray setup ----
  float ox = rays_o[ray*3], oy = rays_o[ray*3+1], oz = rays_o[ray*3+2];
  float dx = rays_d[ray*3], dy = rays_d[ray*3+1], dz = rays_d[ray*3+2];
  float tnx = (-1.f-ox)/(dx+1e-15f), tfx = (1.f-ox)/(dx+1e-15f);
  float tny = (-1.f-oy)/(dy+1e-15f), tfy = (1.f-oy)/(dy+1e-15f);
  float tnz = (-1.f-oz)/(dz+1e-15f), tfz = (1.f-oz)/(dz+1e-15f);
  float nearv = fmaxf(fmaxf(fminf(tnx,tfx), fminf(tny,tfy)), fminf(tnz,tfz));
  float farv  = fminf(fminf(fmaxf(tnx,tfx), fmaxf(tny,tfy)), fmaxf(tnz,tfz));
  nearv = fmaxf(nearv, 0.05f);
  const float sd = (farv - nearv) * (1.f/64.f);

  // ---- coarse pass: wave 0 of each ray (lane = coarse sample) ----
  if (wir == 0){
    float zt = nearv + (farv-nearv) * ((float)lane * (1.f/63.f));
    float px = clampf(ox + dx*zt, -1.f, 1.f);
    float py = clampf(oy + dy*zt, -1.f, 1.f);
    float pz = clampf(oz + dz*zt, -1.f, 1.f);
    float acc = b20;
    #pragma unroll 8
    for (int j = 0; j < 64; ++j){
      float4 w = pW1[j];
      acc += fmaxf(px*w.x + py*w.y + pz*w.z + w.w, 0.f) * ws[OFF_W1E + 4*j + 3];
    }
    s_z[rs][lane] = zt;
    float s1  = __shfl_down(acc, 1);
    float zt1 = nearv + (farv-nearv) * ((float)(lane+1) * (1.f/63.f));
    float a_c = 0.f, qv = 1.f;
    if (lane < 63){
      float dc   = zt1 - zt;
      float mid  = 0.5f*(acc + s1);
      float cosv = clampf((s1-acc)/(dc+1e-5f), -1000.f, 0.f);
      float est  = cosv*dc*0.5f;
      float pcv  = sigm((mid-est)*64.f);
      float ncv  = sigm((mid+est)*64.f);
      a_c = clampf((pcv-ncv+1e-5f)/(pcv+1e-5f), 0.f, 1.f);
      qv  = 1.f - a_c + 1e-7f;
    }
    float p = qv;
    #pragma unroll
    for (int off = 1; off < 64; off <<= 1){
      float t = __shfl_up(p, off);
      if (lane >= off) p *= t;
    }
    float ec = __shfl_up(p, 1);
    if (lane == 0) ec = 1.f;
    float wvv = (lane < 63) ? (a_c*ec + 1e-5f) : 0.f;
    float tot = wvv;
    #pragma unroll
    for (int off = 32; off > 0; off >>= 1) tot += __shfl_xor(tot, off);
    float cs = wvv;
    #pragma unroll
    for (int off = 1; off < 64; off <<= 1){
      float t = __shfl_up(cs, off);
      if (lane >= off) cs += t;
    }
    if (lane == 0)  s_cdf[rs][0] = 0.f;
    if (lane < 63)  s_cdf[rs][lane+1] = cs / tot;
  }
  __syncthreads();

  // ---- sample_pdf (searchsorted right + lerp) ----
  if (wir == 0){
    float u = ((float)lane + 0.5f) * (1.f/64.f);
    int lo = 0, hi = 64;
    while (lo < hi){
      int m = (lo+hi) >> 1;
      if (s_cdf[rs][m] <= u) lo = m+1; else hi = m;
    }
    int below = lo - 1;
    int above = lo < 63 ? lo : 63;
    float cb = s_cdf[rs][below], ca = s_cdf[rs][above];
    float bb = s_z[rs][below],   ba = s_z[rs][above];
    float den = ca - cb; if (den < 1e-5f) den = 1.f;
    float tt = (u - cb)/den;
    s_newz[rs][lane] = bb + tt*(ba - bb);
  }
  __syncthreads();

  // ---- parallel merge of two sorted 64-lists ----
  {
    float v; int pos;
    if (lt < 64){
      v = s_z[rs][lt];
      int lo = 0, hi = 64;
      while (lo < hi){ int m=(lo+hi)>>1; if (s_newz[rs][m] < v) lo = m+1; else hi = m; }
      pos = lt + lo;
    } else {
      int jj = lt - 64;
      v = s_newz[rs][jj];
      int lo = 0, hi = 64;
      while (lo < hi){ int m=(lo+hi)>>1; if (s_z[rs][m] <= v) lo = m+1; else hi = m; }
      pos = jj + lo;
    }
    s_zall[rs][pos] = v;
  }
  __syncthreads();

  // ---- fine pass ----
  float zc = s_zall[rs][lt];
  float zn = s_zall[rs][lt < 127 ? lt+1 : 127];
  float delta = (lt < 127) ? (zn - zc) : sd;
  float zm    = (lt < 127) ? (zc + 0.5f*delta) : zc;
  float px = clampf(ox + dx*zm, -1.f, 1.f);
  float py = clampf(oy + dy*zm, -1.f, 1.f);
  float pz = clampf(oz + dz*zm, -1.f, 1.f);

  // layer-1 + sdf col-0 + 6-point FD grad; hv -> LDS row (bf16 pairs)
  unsigned short* arow = &s_aext[wv][(unsigned)lane * KS];
  float sa = b20;
  float a0=b20,a1=b20,a2=b20,a3=b20,a4=b20,a5=b20;
  #pragma unroll 2
  for (int j2 = 0; j2 < 32; ++j2){
    int j = 2*j2;
    float4 w0 = pW1[j],   e0 = pW1E[j];
    float4 w1 = pW1[j+1], e1 = pW1E[j+1];
    float base0 = fmaf(px, w0.x, fmaf(py, w0.y, fmaf(pz, w0.z, w0.w)));
    float base1 = fmaf(px, w1.x, fmaf(py, w1.y, fmaf(pz, w1.z, w1.w)));
    float hv0 = fmaxf(base0, 0.f), hv1 = fmaxf(base1, 0.f);
    sa = fmaf(hv0, e0.w, sa); sa = fmaf(hv1, e1.w, sa);
    a0 = fmaf(fmaxf(base0+e0.x,0.f), e0.w, a0); a0 = fmaf(fmaxf(base1+e1.x,0.f), e1.w, a0);
    a1 = fmaf(fmaxf(base0-e0.x,0.f), e0.w, a1); a1 = fmaf(fmaxf(base1-e1.x,0.f), e1.w, a1);
    a2 = fmaf(fmaxf(base0+e0.y,0.f), e0.w, a2); a2 = fmaf(fmaxf(base1+e1.y,0.f), e1.w, a2);
    a3 = fmaf(fmaxf(base0-e0.y,0.f), e0.w, a3); a3 = fmaf(fmaxf(base1-e1.y,0.f), e1.w, a3);
    a4 = fmaf(fmaxf(base0+e0.z,0.f), e0.w, a4); a4 = fmaf(fmaxf(base1+e1.z,0.f), e1.w, a4);
    a5 = fmaf(fmaxf(base0-e0.z,0.f), e0.w, a5); a5 = fmaf(fmaxf(base1-e1.z,0.f), e1.w, a5);
    *(unsigned*)&arow[j] = pk2(hv0, hv1);
  }
  float sdfv = sa;
  float gx = (a0-a1)*100.f, gy = (a2-a3)*100.f, gz = (a4-a5)*100.f;
  float gn = 1e-5f + sqrtf(gx*gx + gy*gy + gz*gz);
  float nx = gx/gn, ny = gy/gn, nz = gz/gn;

  // ext slots: k=64..72 = [pt,dir,n], k=73 = 1, k=74..79 = 0
  *(unsigned*)&arow[64] = pk2(px, py);
  *(unsigned*)&arow[66] = pk2(pz, dx);
  *(unsigned*)&arow[68] = pk2(dy, dz);
  *(unsigned*)&arow[70] = pk2(nx, ny);
  *(unsigned*)&arow[72] = pk2(nz, 1.0f);
  *(unsigned*)&arow[74] = 0u;
  *(unsigned*)&arow[76] = 0u;
  *(unsigned*)&arow[78] = 0u;

  // A-fragments (weights, pre-swizzled bf16) — lane-varying global loads
  const short8v* pAF = (const short8v*)(ws + OFF_AF);
  short8v af[10];
  #pragma unroll
  for (int f = 0; f < 10; ++f) af[f] = pAF[f*64 + lane];

  __builtin_amdgcn_wave_barrier();   // keep ds writes above ds reads below

  // MFMA: C[c][s] = A(64x80) x aext^T(80x64), tiles (mb over c, nb over s)
  f32x16 acc00, acc01, acc10, acc11;
  #pragma unroll
  for (int i = 0; i < 16; ++i){ acc00[i]=0.f; acc01[i]=0.f; acc10[i]=0.f; acc11[i]=0.f; }
  const unsigned short* aw = s_aext[wv];
  const int scol = lane & 31;
  const int half8 = (lane >> 5) * 8;
  #pragma unroll
  for (int kk = 0; kk < 5; ++kk){
    int koff = 16*kk + half8;
    short8v b0 = lds_load8(&aw[ scol      * KS + koff]);
    short8v b1 = lds_load8(&aw[(32+scol) * KS + koff]);
    acc00 = __builtin_amdgcn_mfma_f32_32x32x16_bf16(af[kk],   b0, acc00, 0, 0, 0);
    acc10 = __builtin_amdgcn_mfma_f32_32x32x16_bf16(af[5+kk], b0, acc10, 0, 0, 0);
    acc01 = __builtin_amdgcn_mfma_f32_32x32x16_bf16(af[kk],   b1, acc01, 0, 0, 0);
    acc11 = __builtin_amdgcn_mfma_f32_32x32x16_bf16(af[5+kk], b1, acc11, 0, 0, 0);
  }

  // relu -> *Wc2 -> reduce over c: in-lane over regs, cross-half via shfl_xor(32)
  float pr0=0.f,pr1=0.f,pr2=0.f,pr3=0.f,pr4=0.f,pr5=0.f;
  const int halfoff = (lane >> 5) * 4;
  #pragma unroll
  for (int r = 0; r < 16; ++r){
    int ci = (r & 3) + 8*(r >> 2) + halfoff;
    float4 wA = s_wc2[ci];
    float4 wB = s_wc2[32 + ci];
    float v;
    v = fmaxf(acc00[r], 0.f); pr0 = fmaf(v, wA.x, pr0); pr1 = fmaf(v, wA.y, pr1); pr2 = fmaf(v, wA.z, pr2);
    v = fmaxf(acc10[r], 0.f); pr0 = fmaf(v, wB.x, pr0); pr1 = fmaf(v, wB.y, pr1); pr2 = fmaf(v, wB.z, pr2);
    v = fmaxf(acc01[r], 0.f); pr3 = fmaf(v, wA.x, pr3); pr4 = fmaf(v, wA.y, pr4); pr5 = fmaf(v, wA.z, pr5);
    v = fmaxf(acc11[r], 0.f); pr3 = fmaf(v, wB.x, pr3); pr4 = fmaf(v, wB.y, pr4); pr5 = fmaf(v, wB.z, pr5);
  }
  pr0 += __shfl_xor(pr0, 32); pr1 += __shfl_xor(pr1, 32); pr2 += __shfl_xor(pr2, 32);
  pr3 += __shfl_xor(pr3, 32); pr4 += __shfl_xor(pr4, 32); pr5 += __shfl_xor(pr5, 32);
  const bool hihalf = (lane >= 32);
  float c0 = sigm((hihalf ? pr3 : pr0) + pbc2[0]);
  float c1 = sigm((hihalf ? pr4 : pr1) + pbc2[1]);
  float c2 = sigm((hihalf ? pr5 : pr2) + pbc2[2]);

  // NeuS alpha (fp32 path, unchanged)
  const float inv_s = expf(10.f * inv_s_p[0]);
  float tcos = dx*nx + dy*ny + dz*nz;
  float aarg = -100.f * tcos;
  float spv  = (aarg > 0.f) ? (aarg + log1pf(expf(-aarg))) : log1pf(expf(aarg));
  float iter_cos = -(spv * 0.01f);
  float est = iter_cos * delta * 0.5f;
  float pcv = sigm((sdfv - est)*inv_s);
  float ncv = sigm((sdfv + est)*inv_s);
  float alpha = clampf((pcv - ncv + 1e-5f)/(pcv + 1e-5f), 0.f, 1.f);

  // transmittance scan over 128 samples (2 waves) + composite
  float qv = 1.f - alpha + 1e-7f;
  float p = qv;
  #pragma unroll
  for (int off = 1; off < 64; off <<= 1){
    float t = __shfl_up(p, off);
    if (lane >= off) p *= t;
  }
  if (lane == 63) s_wtot[rs][wir] = p;
  __syncthreads();
  float excl = __shfl_up(p, 1);
  if (lane == 0) excl = 1.f;
  if (wir == 1) excl *= s_wtot[rs][0];
  float w  = alpha * excl;
  float r0 = w, r1 = w*c0, r2 = w*c1, r3 = w*c2;
  #pragma unroll
  for (int off = 32; off > 0; off >>= 1){
    r0 += __shfl_xor(r0, off);
    r1 += __shfl_xor(r1, off);
    r2 += __shfl_xor(r2, off);
    r3 += __shfl_xor(r3, off);
  }
  if (lane == 0){
    s_red[rs][wir][0]=r0; s_red[rs][wir][1]=r1; s_red[rs][wir][2]=r2; s_red[rs][wir][3]=r3;
  }
  __syncthreads();
  if (lt == 0){
    float wsum = s_red[rs][0][0] + s_red[rs][1][0];
    float bg = 1.f - wsum;
    out[ray*3+0] = s_red[rs][0][1] + s_red[rs][1][1] + bg;
    out[ray*3+1] = s_red[rs][0][2] + s_red[rs][1][2] + bg;
    out[ray*3+2] = s_red[rs][0][3] + s_red[rs][1][3] + bg;
  }
}

extern "C" void kernel_launch(void* const* d_in, const int* in_sizes, int n_in,
                              void* d_out, int out_size, void* d_ws, size_t ws_size,
                              hipStream_t stream)
{
  const float* rays_o = (const float*)d_in[0];
  const float* rays_d = (const float*)d_in[1];
  const float* W1  = (const float*)d_in[2];
  const float* b1  = (const float*)d_in[3];
  const float* W2  = (const float*)d_in[4];
  const float* b2  = (const float*)d_in[5];
  const float* Wc1 = (const float*)d_in[6];
  const float* bc1 = (const float*)d_in[7];
  const float* Wc2 = (const float*)d_in[8];
  const float* bc2 = (const float*)d_in[9];
  const float* inv_s = (const float*)d_in[10];
  float* out = (float*)d_out;
  float* ws  = (float*)d_ws;

  prep_weights<<<4, 256, 0, stream>>>(W1, b1, W2, b2, Wc1, bc1, Wc2, bc2, ws);

  const int R = in_sizes[0] / 3;               // 4096 rays
  dim3 grid(R / RAYS_PER_BLOCK), block(256);
  neus_render<<<grid, block, 0, stream>>>(rays_o, rays_d, inv_s, ws, out);
}

// Round 5
// 133.201 us; speedup vs baseline: 2.5747x; 1.0946x over previous
//
#include <hip/hip_runtime.h>
#include <hip/hip_bf16.h>
#include <cmath>

#define RAYS_PER_BLOCK 2
#define KS 84   // aext row stride in ushorts (bank-decorrelated, 8B-aligned rows)

// ---- packed-weight layout in d_ws (float offsets) ----
#define OFF_W1    0      // 64 x float4 {W1[0][j],W1[1][j],W1[2][j],b1[j]}
#define OFF_W1E   256    // 64 x float4 {eps*W1x, eps*W1y, eps*W1z, W2[j][0]}
#define OFF_WC2   512    // 64 x float4 {Wc2[c][0..2], 0}
#define OFF_BC2   768    // {bc2[0],bc2[1],bc2[2], b2[0]}
#define OFF_AF    772    // 10 frags x 64 lanes x 8 bf16, A-operand-swizzled (16B/lane/frag)

typedef __attribute__((ext_vector_type(4))) short  short4v;
typedef __attribute__((ext_vector_type(8))) short  short8v;
typedef __attribute__((ext_vector_type(16))) float f32x16;

__device__ __forceinline__ float sigm(float x){ return 1.0f/(1.0f + expf(-x)); }
__device__ __forceinline__ float clampf(float x, float lo, float hi){ return fminf(fmaxf(x, lo), hi); }
__device__ __forceinline__ unsigned short f2bf(float x){
  __hip_bfloat16 h = __float2bfloat16(x);
  return *reinterpret_cast<unsigned short*>(&h);
}
__device__ __forceinline__ unsigned pk2(float a, float b){
  return (unsigned)f2bf(a) | ((unsigned)f2bf(b) << 16);
}
__device__ __forceinline__ short8v lds_load8(const unsigned short* p){
  short4v lo = *(const short4v*)p;
  short4v hi = *(const short4v*)(p + 4);
  short8v r;
  r[0]=lo[0]; r[1]=lo[1]; r[2]=lo[2]; r[3]=lo[3];
  r[4]=hi[0]; r[5]=hi[1]; r[6]=hi[2]; r[7]=hi[3];
  return r;
}

// A[c][k]: k<64 -> M[k][c]=sum_t W2[k][1+t]*Wc1[9+t][c]; k=64..72 -> Wc1[k-64][c];
// k=73 -> cb[c]=bc1[c]+sum_t b2[1+t]*Wc1[9+t][c]; k>=74 -> 0.
// LDS-staged: W2/Wc1 read once coalesced into LDS, dots run from LDS (broadcast-friendly).
__global__ __launch_bounds__(256)
void prep_weights(const float* __restrict__ W1, const float* __restrict__ b1,
                  const float* __restrict__ W2, const float* __restrict__ b2,
                  const float* __restrict__ Wc1, const float* __restrict__ bc1,
                  const float* __restrict__ Wc2, const float* __restrict__ bc2,
                  float* __restrict__ ws)
{
  __shared__ float sWc1[64*64];  // [t][c] = Wc1[(9+t)*64 + c]
  __shared__ float sW2[64*64];   // [k][t] = W2[k*65 + 1 + t]
  __shared__ float sB2[64];      // b2[1+t]
  const int tid = threadIdx.x;
  for (int i = tid; i < 4096; i += 256){
    int r = i >> 6, c = i & 63;
    sWc1[i] = Wc1[(9+r)*64 + c];
    sW2[i]  = W2[r*65 + 1 + c];
  }
  if (tid < 64) sB2[tid] = b2[1+tid];
  __syncthreads();

  int g = blockIdx.x * 256 + tid;
  if (g < 640){                       // A-fragment swizzle: frag f=(mb*5+kk), lane ln
    int f = g >> 6, ln = g & 63;
    int mb = f / 5, kk = f - 5*mb;
    int c  = 32*mb + (ln & 31);
    int kbase = 16*kk + 8*(ln >> 5);
    unsigned short* dst = ((unsigned short*)(ws + OFF_AF)) + (size_t)g * 8;
    if (kk < 4){
      // all 8 k's are M-rows: t-outer, 8 accumulators, LDS reads broadcast
      float acc[8];
      #pragma unroll
      for (int j = 0; j < 8; ++j) acc[j] = 0.f;
      for (int t = 0; t < 64; ++t){
        float wv = sWc1[t*64 + c];
        #pragma unroll
        for (int j = 0; j < 8; ++j) acc[j] += sW2[(kbase+j)*64 + t] * wv;
      }
      #pragma unroll
      for (int j = 0; j < 8; ++j) dst[j] = f2bf(acc[j]);
    } else {
      // ext rows: k=64..72 Wc1 rows, k=73 cb, k>=74 zero
      for (int j = 0; j < 8; ++j){
        int k = kbase + j;
        float v;
        if (k < 73){
          v = Wc1[(k-64)*64 + c];
        } else if (k == 73){
          v = bc1[c];
          for (int t = 0; t < 64; ++t) v += sB2[t] * sWc1[t*64 + c];
        } else v = 0.f;
        dst[j] = f2bf(v);
      }
    }
  } else if (g < 704){                // W1 pack
    int j = g - 640;
    ws[OFF_W1 + 4*j + 0] = W1[j];
    ws[OFF_W1 + 4*j + 1] = W1[64+j];
    ws[OFF_W1 + 4*j + 2] = W1[128+j];
    ws[OFF_W1 + 4*j + 3] = b1[j];
  } else if (g < 768){                // W1E pack
    int j = g - 704;
    ws[OFF_W1E + 4*j + 0] = 0.005f * W1[j];
    ws[OFF_W1E + 4*j + 1] = 0.005f * W1[64+j];
    ws[OFF_W1E + 4*j + 2] = 0.005f * W1[128+j];
    ws[OFF_W1E + 4*j + 3] = W2[j*65];
  } else if (g < 832){                // Wc2 pack
    int j = g - 768;
    ws[OFF_WC2 + 4*j + 0] = Wc2[j*3+0];
    ws[OFF_WC2 + 4*j + 1] = Wc2[j*3+1];
    ws[OFF_WC2 + 4*j + 2] = Wc2[j*3+2];
    ws[OFF_WC2 + 4*j + 3] = 0.f;
  } else if (g < 836){                // bc2 + b2[0]
    int j = g - 832;
    ws[OFF_BC2 + j] = (j < 3) ? bc2[j] : b2[0];
  }
}

// One block = 2 rays x 128 threads; thread lt = fine sample; wave = 64 samples.
__global__ __launch_bounds__(256)
void neus_render(const float* __restrict__ rays_o, const float* __restrict__ rays_d,
                 const float* __restrict__ inv_s_p, const float* __restrict__ ws,
                 float* __restrict__ out)
{
  __shared__ unsigned short s_aext[4][64*KS];   // per-wave activation rows (bf16)
  __shared__ float4 s_wc2[64];
  __shared__ float  s_z[RAYS_PER_BLOCK][64];
  __shared__ float  s_cdf[RAYS_PER_BLOCK][64];
  __shared__ float  s_newz[RAYS_PER_BLOCK][64];
  __shared__ float  s_zall[RAYS_PER_BLOCK][128];
  __shared__ float  s_red[RAYS_PER_BLOCK][2][4];
  __shared__ float  s_wtot[RAYS_PER_BLOCK][2];

  const int tid  = threadIdx.x;
  const int rs   = tid >> 7;
  const int lt   = tid & 127;
  const int lane = tid & 63;
  const int wir  = (tid >> 6) & 1;
  const int wv   = tid >> 6;
  const int ray  = blockIdx.x * RAYS_PER_BLOCK + rs;

  const float4* __restrict__ pW1  = (const float4*)(ws + OFF_W1);
  const float4* __restrict__ pW1E = (const float4*)(ws + OFF_W1E);
  const float*  __restrict__ pbc2 = ws + OFF_BC2;
  const float b20 = pbc2[3];

  if (tid < 64) s_wc2[tid] = ((const float4*)(ws + OFF_WC2))[tid];

  // ---- per-ray setup ----
  float ox = rays_o[ray*3], oy = rays_o[ray*3+1], oz = rays_o[ray*3+2];
  float dx = rays_d[ray*3], dy = rays_d[ray*3+1], dz = rays_d[ray*3+2];
  float tnx = (-1.f-ox)/(dx+1e-15f), tfx = (1.f-ox)/(dx+1e-15f);
  float tny = (-1.f-oy)/(dy+1e-15f), tfy = (1.f-oy)/(dy+1e-15f);
  float tnz = (-1.f-oz)/(dz+1e-15f), tfz = (1.f-oz)/(dz+1e-15f);
  float nearv = fmaxf(fmaxf(fminf(tnx,tfx), fminf(tny,tfy)), fminf(tnz,tfz));
  float farv  = fminf(fminf(fmaxf(tnx,tfx), fmaxf(tny,tfy)), fmaxf(tnz,tfz));
  nearv = fmaxf(nearv, 0.05f);
  const float sd = (farv - nearv) * (1.f/64.f);

  // ---- coarse pass: wave 0 of each ray (lane = coarse sample) ----
  if (wir == 0){
    float zt = nearv + (farv-nearv) * ((float)lane * (1.f/63.f));
    float px = clampf(ox + dx*zt, -1.f, 1.f);
    float py = clampf(oy + dy*zt, -1.f, 1.f);
    float pz = clampf(oz + dz*zt, -1.f, 1.f);
    float acc = b20;
    #pragma unroll 8
    for (int j = 0; j < 64; ++j){
      float4 w = pW1[j];
      acc += fmaxf(px*w.x + py*w.y + pz*w.z + w.w, 0.f) * ws[OFF_W1E + 4*j + 3];
    }
    s_z[rs][lane] = zt;
    float s1  = __shfl_down(acc, 1);
    float zt1 = nearv + (farv-nearv) * ((float)(lane+1) * (1.f/63.f));
    float a_c = 0.f, qv = 1.f;
    if (lane < 63){
      float dc   = zt1 - zt;
      float mid  = 0.5f*(acc + s1);
      float cosv = clampf((s1-acc)/(dc+1e-5f), -1000.f, 0.f);
      float est  = cosv*dc*0.5f;
      float pcv  = sigm((mid-est)*64.f);
      float ncv  = sigm((mid+est)*64.f);
      a_c = clampf((pcv-ncv+1e-5f)/(pcv+1e-5f), 0.f, 1.f);
      qv  = 1.f - a_c + 1e-7f;
    }
    float p = qv;
    #pragma unroll
    for (int off = 1; off < 64; off <<= 1){
      float t = __shfl_up(p, off);
      if (lane >= off) p *= t;
    }
    float ec = __shfl_up(p, 1);
    if (lane == 0) ec = 1.f;
    float wvv = (lane < 63) ? (a_c*ec + 1e-5f) : 0.f;
    float tot = wvv;
    #pragma unroll
    for (int off = 32; off > 0; off >>= 1) tot += __shfl_xor(tot, off);
    float cs = wvv;
    #pragma unroll
    for (int off = 1; off < 64; off <<= 1){
      float t = __shfl_up(cs, off);
      if (lane >= off) cs += t;
    }
    if (lane == 0)  s_cdf[rs][0] = 0.f;
    if (lane < 63)  s_cdf[rs][lane+1] = cs / tot;
  }
  __syncthreads();

  // ---- sample_pdf (searchsorted right + lerp) ----
  if (wir == 0){
    float u = ((float)lane + 0.5f) * (1.f/64.f);
    int lo = 0, hi = 64;
    while (lo < hi){
      int m = (lo+hi) >> 1;
      if (s_cdf[rs][m] <= u) lo = m+1; else hi = m;
    }
    int below = lo - 1;
    int above = lo < 63 ? lo : 63;
    float cb = s_cdf[rs][below], ca = s_cdf[rs][above];
    float bb = s_z[rs][below],   ba = s_z[rs][above];
    float den = ca - cb; if (den < 1e-5f) den = 1.f;
    float tt = (u - cb)/den;
    s_newz[rs][lane] = bb + tt*(ba - bb);
  }
  __syncthreads();

  // A-fragments (weights, pre-swizzled bf16) — issue early to overlap latency
  const short8v* pAF = (const short8v*)(ws + OFF_AF);
  short8v af[10];
  #pragma unroll
  for (int f = 0; f < 10; ++f) af[f] = pAF[f*64 + lane];

  // ---- parallel merge of two sorted 64-lists ----
  {
    float v; int pos;
    if (lt < 64){
      v = s_z[rs][lt];
      int lo = 0, hi = 64;
      while (lo < hi){ int m=(lo+hi)>>1; if (s_newz[rs][m] < v) lo = m+1; else hi = m; }
      pos = lt + lo;
    } else {
      int jj = lt - 64;
      v = s_newz[rs][jj];
      int lo = 0, hi = 64;
      while (lo < hi){ int m=(lo+hi)>>1; if (s_z[rs][m] <= v) lo = m+1; else hi = m; }
      pos = jj + lo;
    }
    s_zall[rs][pos] = v;
  }
  __syncthreads();

  // ---- fine pass ----
  float zc = s_zall[rs][lt];
  float zn = s_zall[rs][lt < 127 ? lt+1 : 127];
  float delta = (lt < 127) ? (zn - zc) : sd;
  float zm    = (lt < 127) ? (zc + 0.5f*delta) : zc;
  float px = clampf(ox + dx*zm, -1.f, 1.f);
  float py = clampf(oy + dy*zm, -1.f, 1.f);
  float pz = clampf(oz + dz*zm, -1.f, 1.f);

  // layer-1 + sdf col-0 + 6-point FD grad; hv -> LDS row (bf16 pairs)
  unsigned short* arow = &s_aext[wv][(unsigned)lane * KS];
  float sa = b20;
  float a0=b20,a1=b20,a2=b20,a3=b20,a4=b20,a5=b20;
  #pragma unroll 2
  for (int j2 = 0; j2 < 32; ++j2){
    int j = 2*j2;
    float4 w0 = pW1[j],   e0 = pW1E[j];
    float4 w1 = pW1[j+1], e1 = pW1E[j+1];
    float base0 = fmaf(px, w0.x, fmaf(py, w0.y, fmaf(pz, w0.z, w0.w)));
    float base1 = fmaf(px, w1.x, fmaf(py, w1.y, fmaf(pz, w1.z, w1.w)));
    float hv0 = fmaxf(base0, 0.f), hv1 = fmaxf(base1, 0.f);
    sa = fmaf(hv0, e0.w, sa); sa = fmaf(hv1, e1.w, sa);
    a0 = fmaf(fmaxf(base0+e0.x,0.f), e0.w, a0); a0 = fmaf(fmaxf(base1+e1.x,0.f), e1.w, a0);
    a1 = fmaf(fmaxf(base0-e0.x,0.f), e0.w, a1); a1 = fmaf(fmaxf(base1-e1.x,0.f), e1.w, a1);
    a2 = fmaf(fmaxf(base0+e0.y,0.f), e0.w, a2); a2 = fmaf(fmaxf(base1+e1.y,0.f), e1.w, a2);
    a3 = fmaf(fmaxf(base0-e0.y,0.f), e0.w, a3); a3 = fmaf(fmaxf(base1-e1.y,0.f), e1.w, a3);
    a4 = fmaf(fmaxf(base0+e0.z,0.f), e0.w, a4); a4 = fmaf(fmaxf(base1+e1.z,0.f), e1.w, a4);
    a5 = fmaf(fmaxf(base0-e0.z,0.f), e0.w, a5); a5 = fmaf(fmaxf(base1-e1.z,0.f), e1.w, a5);
    *(unsigned*)&arow[j] = pk2(hv0, hv1);
  }
  float sdfv = sa;
  float gx = (a0-a1)*100.f, gy = (a2-a3)*100.f, gz = (a4-a5)*100.f;
  float gn = 1e-5f + sqrtf(gx*gx + gy*gy + gz*gz);
  float nx = gx/gn, ny = gy/gn, nz = gz/gn;

  // ext slots: k=64..72 = [pt,dir,n], k=73 = 1, k=74..79 = 0
  *(unsigned*)&arow[64] = pk2(px, py);
  *(unsigned*)&arow[66] = pk2(pz, dx);
  *(unsigned*)&arow[68] = pk2(dy, dz);
  *(unsigned*)&arow[70] = pk2(nx, ny);
  *(unsigned*)&arow[72] = pk2(nz, 1.0f);
  *(unsigned*)&arow[74] = 0u;
  *(unsigned*)&arow[76] = 0u;
  *(unsigned*)&arow[78] = 0u;

  __builtin_amdgcn_wave_barrier();   // keep ds writes above ds reads below

  // MFMA: C[c][s] = A(64x80) x aext^T(80x64), tiles (mb over c, nb over s)
  f32x16 acc00, acc01, acc10, acc11;
  #pragma unroll
  for (int i = 0; i < 16; ++i){ acc00[i]=0.f; acc01[i]=0.f; acc10[i]=0.f; acc11[i]=0.f; }
  const unsigned short* aw = s_aext[wv];
  const int scol = lane & 31;
  const int half8 = (lane >> 5) * 8;
  #pragma unroll
  for (int kk = 0; kk < 5; ++kk){
    int koff = 16*kk + half8;
    short8v b0 = lds_load8(&aw[ scol      * KS + koff]);
    short8v b1 = lds_load8(&aw[(32+scol) * KS + koff]);
    acc00 = __builtin_amdgcn_mfma_f32_32x32x16_bf16(af[kk],   b0, acc00, 0, 0, 0);
    acc10 = __builtin_amdgcn_mfma_f32_32x32x16_bf16(af[5+kk], b0, acc10, 0, 0, 0);
    acc01 = __builtin_amdgcn_mfma_f32_32x32x16_bf16(af[kk],   b1, acc01, 0, 0, 0);
    acc11 = __builtin_amdgcn_mfma_f32_32x32x16_bf16(af[5+kk], b1, acc11, 0, 0, 0);
  }

  // relu -> *Wc2 -> reduce over c: in-lane over regs, cross-half via shfl_xor(32)
  float pr0=0.f,pr1=0.f,pr2=0.f,pr3=0.f,pr4=0.f,pr5=0.f;
  const int halfoff = (lane >> 5) * 4;
  #pragma unroll
  for (int r = 0; r < 16; ++r){
    int ci = (r & 3) + 8*(r >> 2) + halfoff;
    float4 wA = s_wc2[ci];
    float4 wB = s_wc2[32 + ci];
    float v;
    v = fmaxf(acc00[r], 0.f); pr0 = fmaf(v, wA.x, pr0); pr1 = fmaf(v, wA.y, pr1); pr2 = fmaf(v, wA.z, pr2);
    v = fmaxf(acc10[r], 0.f); pr0 = fmaf(v, wB.x, pr0); pr1 = fmaf(v, wB.y, pr1); pr2 = fmaf(v, wB.z, pr2);
    v = fmaxf(acc01[r], 0.f); pr3 = fmaf(v, wA.x, pr3); pr4 = fmaf(v, wA.y, pr4); pr5 = fmaf(v, wA.z, pr5);
    v = fmaxf(acc11[r], 0.f); pr3 = fmaf(v, wB.x, pr3); pr4 = fmaf(v, wB.y, pr4); pr5 = fmaf(v, wB.z, pr5);
  }
  pr0 += __shfl_xor(pr0, 32); pr1 += __shfl_xor(pr1, 32); pr2 += __shfl_xor(pr2, 32);
  pr3 += __shfl_xor(pr3, 32); pr4 += __shfl_xor(pr4, 32); pr5 += __shfl_xor(pr5, 32);
  const bool hihalf = (lane >= 32);
  float c0 = sigm((hihalf ? pr3 : pr0) + pbc2[0]);
  float c1 = sigm((hihalf ? pr4 : pr1) + pbc2[1]);
  float c2 = sigm((hihalf ? pr5 : pr2) + pbc2[2]);

  // NeuS alpha (fp32 path, unchanged)
  const float inv_s = expf(10.f * inv_s_p[0]);
  float tcos = dx*nx + dy*ny + dz*nz;
  float aarg = -100.f * tcos;
  float spv  = (aarg > 0.f) ? (aarg + log1pf(expf(-aarg))) : log1pf(expf(aarg));
  float iter_cos = -(spv * 0.01f);
  float est = iter_cos * delta * 0.5f;
  float pcv = sigm((sdfv - est)*inv_s);
  float ncv = sigm((sdfv + est)*inv_s);
  float alpha = clampf((pcv - ncv + 1e-5f)/(pcv + 1e-5f), 0.f, 1.f);

  // transmittance scan over 128 samples (2 waves) + composite
  float qv = 1.f - alpha + 1e-7f;
  float p = qv;
  #pragma unroll
  for (int off = 1; off < 64; off <<= 1){
    float t = __shfl_up(p, off);
    if (lane >= off) p *= t;
  }
  if (lane == 63) s_wtot[rs][wir] = p;
  __syncthreads();
  float excl = __shfl_up(p, 1);
  if (lane == 0) excl = 1.f;
  if (wir == 1) excl *= s_wtot[rs][0];
  float w  = alpha * excl;
  float r0 = w, r1 = w*c0, r2 = w*c1, r3 = w*c2;
  #pragma unroll
  for (int off = 32; off > 0; off >>= 1){
    r0 += __shfl_xor(r0, off);
    r1 += __shfl_xor(r1, off);
    r2 += __shfl_xor(r2, off);
    r3 += __shfl_xor(r3, off);
  }
  if (lane == 0){
    s_red[rs][wir][0]=r0; s_red[rs][wir][1]=r1; s_red[rs][wir][2]=r2; s_red[rs][wir][3]=r3;
  }
  __syncthreads();
  if (lt == 0){
    float wsum = s_red[rs][0][0] + s_red[rs][1][0];
    float bg = 1.f - wsum;
    out[ray*3+0] = s_red[rs][0][1] + s_red[rs][1][1] + bg;
    out[ray*3+1] = s_red[rs][0][2] + s_red[rs][1][2] + bg;
    out[ray*3+2] = s_red[rs][0][3] + s_red[rs][1][3] + bg;
  }
}

extern "C" void kernel_launch(void* const* d_in, const int* in_sizes, int n_in,
                              void* d_out, int out_size, void* d_ws, size_t ws_size,
                              hipStream_t stream)
{
  const float* rays_o = (const float*)d_in[0];
  const float* rays_d = (const float*)d_in[1];
  const float* W1  = (const float*)d_in[2];
  const float* b1  = (const float*)d_in[3];
  const float* W2  = (const float*)d_in[4];
  const float* b2  = (const float*)d_in[5];
  const float* Wc1 = (const float*)d_in[6];
  const float* bc1 = (const float*)d_in[7];
  const float* Wc2 = (const float*)d_in[8];
  const float* bc2 = (const float*)d_in[9];
  const float* inv_s = (const float*)d_in[10];
  float* out = (float*)d_out;
  float* ws  = (float*)d_ws;

  prep_weights<<<4, 256, 0, stream>>>(W1, b1, W2, b2, Wc1, bc1, Wc2, bc2, ws);

  const int R = in_sizes[0] / 3;               // 4096 rays
  dim3 grid(R / RAYS_PER_BLOCK), block(256);
  neus_render<<<grid, block, 0, stream>>>(rays_o, rays_d, inv_s, ws, out);
}